// Round 12
// baseline (211.844 us; speedup 1.0000x reference)
//
#include <hip/hip_runtime.h>
#include <hip/hip_fp16.h>

#define BN_EPS 1e-5f
#define CCH 2048   // edges per scatter block (391 blocks @ 1024 thr -> full CU coverage)
#define NSLICE 32  // stats partial slices (contention limiter)
#define OUT_CAP 8192
#define CAP 8192   // fixed bucket capacity (mean 4096, sd 64 -> >60 sigma margin)
#define SXS 68

// ---------------- fp16 helpers (union puns) ----------------

__device__ inline __half2 u2h(unsigned u) {
    union { unsigned u; __half2 h; } x; x.u = u; return x.h;
}
__device__ inline unsigned h2u(__half2 h) {
    union { unsigned u; __half2 h; } x; x.h = h; return x.u;
}
__device__ inline unsigned pack_f16x2(float a, float b) {
    return h2u(__floats2half2_rn(a, b));
}

// ================= Phase A: direct scatter into fixed-capacity buckets =================
// 1024 threads/block, 2048 edges/block: 2 edge iters; full CU coverage.

__global__ __launch_bounds__(1024) void scatter_direct(const int* __restrict__ src,
                                                       const int* __restrict__ dst,
                                                       int* __restrict__ ccnt,
                                                       unsigned* __restrict__ tmp,
                                                       float* __restrict__ cnt_g,
                                                       float* __restrict__ out,
                                                       int E, int G) {
    __shared__ int lcnt[256];
    int t = threadIdx.x;
    int tid = blockIdx.x * 1024 + t;
    int stride = gridDim.x * 1024;
    for (int i = tid; i < G * 64; i += stride) out[i] = 0.f;
    for (int i = tid; i < G; i += stride) cnt_g[i] = 0.f;

    int e0 = blockIdx.x * CCH;
    if (t < 256) lcnt[t] = 0;
    __syncthreads();
#pragma unroll
    for (int k = 0; k < CCH / 1024; ++k) {
        int e = e0 + k * 1024 + t;
        if (e < E) atomicAdd(&lcnt[dst[e] >> 8], 1);
    }
    __syncthreads();
    int c = (t < 256) ? lcnt[t] : 0;
    __syncthreads();
    if (t < 256 && c > 0) lcnt[t] = t * CAP + atomicAdd(&ccnt[t], c);  // absolute run start
    __syncthreads();
#pragma unroll
    for (int k = 0; k < CCH / 1024; ++k) {
        int e = e0 + k * 1024 + t;
        if (e < E) {
            int d = dst[e];
            int pos = atomicAdd(&lcnt[d >> 8], 1);
            tmp[pos] = ((unsigned)src[e] << 8) | (unsigned)(d & 255);
        }
    }
}

// ================= Phase B: per-bucket counting sort -> CSR (rp, deg, u16 col) + dinv
//            1024 threads; barrier-free wave-scan (shfl_up) + 1-barrier combine =========

__global__ __launch_bounds__(1024) void build_csr(const unsigned* __restrict__ tmp,
                                                  const int* __restrict__ ccnt,
                                                  int* __restrict__ rp,
                                                  unsigned short* __restrict__ deg,
                                                  unsigned short* __restrict__ col,
                                                  float* __restrict__ dinv,
                                                  const int* __restrict__ batch,
                                                  float* __restrict__ cnt_g,
                                                  int n, int G) {
    __shared__ int hist[256];
    __shared__ unsigned short outw[OUT_CAP];
    __shared__ int h[512];
    __shared__ int wsum[4];
    int b = blockIdx.x;
    int t = threadIdx.x;
    int beg = b * CAP;
    int m = ccnt[b];
    int end = beg + m;
    if (t < 256) hist[t] = 0;
    __syncthreads();
    for (int e = beg + t; e < end; e += 1024) atomicAdd(&hist[tmp[e] & 255u], 1);
    __syncthreads();
    // exclusive scan over 256 bins: 4 waves scan via shfl_up, then combine
    int v = 0, x = 0;
    if (t < 256) {
        v = hist[t];
        x = v;
#pragma unroll
        for (int off = 1; off < 64; off <<= 1) {
            int y = __shfl_up(x, off, 64);
            if ((t & 63) >= off) x += y;
        }
        if ((t & 63) == 63) wsum[t >> 6] = x;   // wave inclusive total
    }
    __syncthreads();
    if (t < 256) {
        int w = t >> 6;
        int pre = 0;
        if (w > 0) pre += wsum[0];
        if (w > 1) pre += wsum[1];
        if (w > 2) pre += wsum[2];
        int excl = (x + pre) - v;
        int node = b * 256 + t;
        if (node < n) {
            dinv[node] = rsqrtf(1.0f + (float)v);
            rp[node] = beg + excl;
            deg[node] = (unsigned short)v;
        }
        hist[t] = excl;  // becomes cursor
    }
    __syncthreads();
    if (m <= OUT_CAP) {
        for (int e = beg + t; e < end; e += 1024) {
            unsigned p = tmp[e];
            int pos = atomicAdd(&hist[p & 255u], 1);
            outw[pos] = (unsigned short)(p >> 8);
        }
        __syncthreads();
        for (int i = t; i < m; i += 1024) col[beg + i] = outw[i];
    } else {  // overflow fallback (dead for CAP==OUT_CAP, kept for safety)
        for (int e = beg + t; e < end; e += 1024) {
            unsigned p = tmp[e];
            int pos = atomicAdd(&hist[p & 255u], 1);
            col[beg + pos] = (unsigned short)(p >> 8);
        }
    }
    // ---- fused graph-size histogram ----
    if (G <= 512) {
        __syncthreads();
        for (int i = t; i < 512; i += 1024) h[i] = 0;
        __syncthreads();
        for (int i = b * 1024 + t; i < n; i += gridDim.x * 1024)
            atomicAdd(&h[batch[i]], 1);
        __syncthreads();
        for (int i = t; i < G; i += 1024)
            if (h[i]) atomicAdd(&cnt_g[i], (float)h[i]);
    } else {
        for (int i = b * 1024 + t; i < n; i += gridDim.x * 1024)
            atomicAdd(&cnt_g[batch[i]], 1.0f);
    }
}

// ================= GEMM: Hs(fp16) = BNReLU(X) @ W * dinv[row] =================

__global__ __launch_bounds__(256) void gemm64_v2(const float* __restrict__ X,
                                                 const float* __restrict__ W,
                                                 const float* __restrict__ dinv,
                                                 const float* __restrict__ part,
                                                 const float* __restrict__ gamma,
                                                 const float* __restrict__ beta,
                                                 int has_bn, float inv_n,
                                                 unsigned* __restrict__ Hs, int n) {
    __shared__ float sX[64 * SXS];
    __shared__ float sW[64 * SXS];
    __shared__ float s_scsh[128];
    int t = threadIdx.x;
    int c4 = t & 15;
    int base = blockIdx.x * 64;

    if (has_bn) {
        if (t < 128) {
            float s = 0.f;
#pragma unroll
            for (int k = 0; k < NSLICE; ++k) s += part[k * 128 + t];
            s_scsh[t] = s;
        }
        __syncthreads();
        if (t < 64) {
            float mean = s_scsh[t] * inv_n;
            float var = s_scsh[64 + t] * inv_n - mean * mean;
            float sc = gamma[t] * rsqrtf(var + BN_EPS);
            s_scsh[t] = sc;
            s_scsh[64 + t] = beta[t] - mean * sc;
        }
        __syncthreads();
    }

    {
        const float4* W4 = (const float4*)W;
#pragma unroll
        for (int it = 0; it < 4; ++it) {
            int idx = it * 256 + t;
            int r = idx >> 4;
            float4 v = W4[r * 16 + c4];
            *(float4*)&sW[r * SXS + c4 * 4] = v;
        }
    }
    {
        const float4* X4 = (const float4*)X;
        float4 sc4, sh4;
        if (has_bn) {
            sc4 = *(const float4*)&s_scsh[c4 * 4];
            sh4 = *(const float4*)&s_scsh[64 + c4 * 4];
        }
#pragma unroll
        for (int it = 0; it < 4; ++it) {
            int idx = it * 256 + t;
            int r = idx >> 4;
            int grow = base + r;
            float4 v = make_float4(0.f, 0.f, 0.f, 0.f);
            if (grow < n) v = X4[(size_t)grow * 16 + c4];
            if (has_bn) {
                v.x = fmaxf(fmaf(v.x, sc4.x, sh4.x), 0.f);
                v.y = fmaxf(fmaf(v.y, sc4.y, sh4.y), 0.f);
                v.z = fmaxf(fmaf(v.z, sc4.z, sh4.z), 0.f);
                v.w = fmaxf(fmaf(v.w, sc4.w, sh4.w), 0.f);
            }
            *(float4*)&sX[r * SXS + c4 * 4] = v;
        }
    }
    __syncthreads();

    int rgrp = t >> 4;
    float4 acc[4];
#pragma unroll
    for (int ri = 0; ri < 4; ++ri) acc[ri] = make_float4(0.f, 0.f, 0.f, 0.f);

#pragma unroll 4
    for (int k4 = 0; k4 < 16; ++k4) {
        float4 xv[4], wv[4];
#pragma unroll
        for (int ri = 0; ri < 4; ++ri)
            xv[ri] = *(const float4*)&sX[(rgrp + 16 * ri) * SXS + k4 * 4];
#pragma unroll
        for (int kk = 0; kk < 4; ++kk)
            wv[kk] = *(const float4*)&sW[(k4 * 4 + kk) * SXS + c4 * 4];
#pragma unroll
        for (int ri = 0; ri < 4; ++ri) {
            acc[ri].x = fmaf(xv[ri].x, wv[0].x, acc[ri].x);
            acc[ri].y = fmaf(xv[ri].x, wv[0].y, acc[ri].y);
            acc[ri].z = fmaf(xv[ri].x, wv[0].z, acc[ri].z);
            acc[ri].w = fmaf(xv[ri].x, wv[0].w, acc[ri].w);
            acc[ri].x = fmaf(xv[ri].y, wv[1].x, acc[ri].x);
            acc[ri].y = fmaf(xv[ri].y, wv[1].y, acc[ri].y);
            acc[ri].z = fmaf(xv[ri].y, wv[1].z, acc[ri].z);
            acc[ri].w = fmaf(xv[ri].y, wv[1].w, acc[ri].w);
            acc[ri].x = fmaf(xv[ri].z, wv[2].x, acc[ri].x);
            acc[ri].y = fmaf(xv[ri].z, wv[2].y, acc[ri].y);
            acc[ri].z = fmaf(xv[ri].z, wv[2].z, acc[ri].z);
            acc[ri].w = fmaf(xv[ri].z, wv[2].w, acc[ri].w);
            acc[ri].x = fmaf(xv[ri].w, wv[3].x, acc[ri].x);
            acc[ri].y = fmaf(xv[ri].w, wv[3].y, acc[ri].y);
            acc[ri].z = fmaf(xv[ri].w, wv[3].z, acc[ri].z);
            acc[ri].w = fmaf(xv[ri].w, wv[3].w, acc[ri].w);
        }
    }

#pragma unroll
    for (int ri = 0; ri < 4; ++ri) {
        int row = base + rgrp + 16 * ri;
        if (row < n) {
            float dv = dinv[row];
            uint2 o2;
            o2.x = pack_f16x2(acc[ri].x * dv, acc[ri].y * dv);
            o2.y = pack_f16x2(acc[ri].z * dv, acc[ri].w * dv);
            ((uint2*)Hs)[(size_t)row * 16 + c4] = o2;
        }
    }
}

// ================= CSR gather-aggregate: 8 dsts per wave, 8-lane clusters ============
// Self-row hoisted; col-index prefetch; 2-deep double-buffered row-load pipeline
// (va/vb, explicit 2-step body -> all register indices static).

__global__ __launch_bounds__(256) void agg(const uint4* __restrict__ Hs4,
                                           const int* __restrict__ rp,
                                           const unsigned short* __restrict__ deg,
                                           const unsigned short* __restrict__ col,
                                           const float* __restrict__ dinv,
                                           float* __restrict__ Y,
                                           float* __restrict__ part, int n) {
    __shared__ float sS[32][64];
    __shared__ float sQ[32][64];
    int t = threadIdx.x;
    int w = t >> 6;
    int lane = t & 63;
    int dslot = lane >> 3;   // dst within wave (0..7)
    int c = lane & 7;        // column chunk (16B of the 128B row) AND index lane
    int slot = w * 8 + dslot;
    int d = blockIdx.x * 32 + slot;
    bool valid = d < n;
    int dc = valid ? d : 0;
    uint4 hv = make_uint4(0u, 0u, 0u, 0u);
    if (valid) hv = Hs4[(size_t)dc * 8 + c];
    __half2 a0 = u2h(0u), a1 = u2h(0u), a2 = u2h(0u), a3 = u2h(0u);
    int beg = 0, end = 0;
    if (valid) { beg = rp[dc]; end = beg + (int)deg[dc]; }
    int b = beg;
    int m = min(8, end - b);
    int idx0 = (c < m) ? (int)col[b + c] : 0;
    uint4 va[8], vb[8];
    // prologue: issue chunk0 into va
#pragma unroll
    for (int k = 0; k < 8; ++k) {
        int s0 = __shfl(idx0, k, 8);
        if (k < m) va[k] = Hs4[(size_t)s0 * 8 + c];
    }
    int bn = b + 8;
    int mn = min(8, end - bn);
    int idxN = (c < mn) ? (int)col[bn + c] : 0;
    while (b < end) {
        // --- step 1: issue next chunk into vb, consume va ---
#pragma unroll
        for (int k = 0; k < 8; ++k) {
            int s0 = __shfl(idxN, k, 8);
            if (k < mn) vb[k] = Hs4[(size_t)s0 * 8 + c];
        }
        {
            int b3 = bn + 8;
            int m3 = min(8, end - b3);
            int idx3 = (c < m3) ? (int)col[b3 + c] : 0;
#pragma unroll
            for (int k = 0; k < 8; ++k) {
                if (k < m) {
                    a0 = __hadd2(a0, u2h(va[k].x)); a1 = __hadd2(a1, u2h(va[k].y));
                    a2 = __hadd2(a2, u2h(va[k].z)); a3 = __hadd2(a3, u2h(va[k].w));
                }
            }
            b = bn; m = mn; bn = b3; mn = m3; idxN = idx3;
        }
        if (b >= end) break;
        // --- step 2: issue next chunk into va, consume vb ---
#pragma unroll
        for (int k = 0; k < 8; ++k) {
            int s0 = __shfl(idxN, k, 8);
            if (k < mn) va[k] = Hs4[(size_t)s0 * 8 + c];
        }
        {
            int b3 = bn + 8;
            int m3 = min(8, end - b3);
            int idx3 = (c < m3) ? (int)col[b3 + c] : 0;
#pragma unroll
            for (int k = 0; k < 8; ++k) {
                if (k < m) {
                    a0 = __hadd2(a0, u2h(vb[k].x)); a1 = __hadd2(a1, u2h(vb[k].y));
                    a2 = __hadd2(a2, u2h(vb[k].z)); a3 = __hadd2(a3, u2h(vb[k].w));
                }
            }
            b = bn; m = mn; bn = b3; mn = m3; idxN = idx3;
        }
    }
    // every lane holds the complete sums for its 8 columns -- no reduction needed
    float2 f0 = __half22float2(a0), f1 = __half22float2(a1);
    float2 f2 = __half22float2(a2), f3 = __half22float2(a3);
    float y0 = f0.x, y1 = f0.y, y2 = f1.x, y3 = f1.y;
    float y4 = f2.x, y5 = f2.y, y6 = f3.x, y7 = f3.y;
    if (valid) {
        float2 h0 = __half22float2(u2h(hv.x)), h1 = __half22float2(u2h(hv.y));
        float2 h2v = __half22float2(u2h(hv.z)), h3 = __half22float2(u2h(hv.w));
        float dv = dinv[dc];
        y0 = (y0 + h0.x) * dv; y1 = (y1 + h0.y) * dv;
        y2 = (y2 + h1.x) * dv; y3 = (y3 + h1.y) * dv;
        y4 = (y4 + h2v.x) * dv; y5 = (y5 + h2v.y) * dv;
        y6 = (y6 + h3.x) * dv; y7 = (y7 + h3.y) * dv;
        *(float4*)&Y[(size_t)dc * 64 + c * 8]     = make_float4(y0, y1, y2, y3);
        *(float4*)&Y[(size_t)dc * 64 + c * 8 + 4] = make_float4(y4, y5, y6, y7);
    } else {
        y0 = y1 = y2 = y3 = y4 = y5 = y6 = y7 = 0.f;
    }
    *(float4*)&sS[slot][c * 8]     = make_float4(y0, y1, y2, y3);
    *(float4*)&sS[slot][c * 8 + 4] = make_float4(y4, y5, y6, y7);
    *(float4*)&sQ[slot][c * 8]     = make_float4(y0 * y0, y1 * y1, y2 * y2, y3 * y3);
    *(float4*)&sQ[slot][c * 8 + 4] = make_float4(y4 * y4, y5 * y5, y6 * y6, y7 * y7);
    __syncthreads();
    if (t < 64) {
        float s = 0.f, qq = 0.f;
#pragma unroll
        for (int i = 0; i < 32; ++i) { s += sS[i][t]; qq += sQ[i][t]; }
        float* dst = part + (size_t)(blockIdx.x & (NSLICE - 1)) * 128;
        atomicAdd(&dst[t], s);
        atomicAdd(&dst[64 + t], qq);
    }
}

// layer-3 variant: no Y materialization; per-graph raw-y sums via atomics.
__global__ __launch_bounds__(256) void agg_pool(const uint4* __restrict__ Hs4,
                                                const int* __restrict__ rp,
                                                const unsigned short* __restrict__ deg,
                                                const unsigned short* __restrict__ col,
                                                const float* __restrict__ dinv,
                                                const int* __restrict__ batch,
                                                float* __restrict__ out,
                                                float* __restrict__ part, int n) {
    __shared__ float sS[32][64];
    __shared__ float sQ[32][64];
    __shared__ int sG[32];
    int t = threadIdx.x;
    int w = t >> 6;
    int lane = t & 63;
    int dslot = lane >> 3;
    int c = lane & 7;
    int slot = w * 8 + dslot;
    int d = blockIdx.x * 32 + slot;
    bool valid = d < n;
    int dc = valid ? d : 0;
    uint4 hv = make_uint4(0u, 0u, 0u, 0u);
    if (valid) hv = Hs4[(size_t)dc * 8 + c];
    __half2 a0 = u2h(0u), a1 = u2h(0u), a2 = u2h(0u), a3 = u2h(0u);
    int beg = 0, end = 0;
    if (valid) { beg = rp[dc]; end = beg + (int)deg[dc]; }
    int b = beg;
    int m = min(8, end - b);
    int idx0 = (c < m) ? (int)col[b + c] : 0;
    uint4 va[8], vb[8];
#pragma unroll
    for (int k = 0; k < 8; ++k) {
        int s0 = __shfl(idx0, k, 8);
        if (k < m) va[k] = Hs4[(size_t)s0 * 8 + c];
    }
    int bn = b + 8;
    int mn = min(8, end - bn);
    int idxN = (c < mn) ? (int)col[bn + c] : 0;
    while (b < end) {
#pragma unroll
        for (int k = 0; k < 8; ++k) {
            int s0 = __shfl(idxN, k, 8);
            if (k < mn) vb[k] = Hs4[(size_t)s0 * 8 + c];
        }
        {
            int b3 = bn + 8;
            int m3 = min(8, end - b3);
            int idx3 = (c < m3) ? (int)col[b3 + c] : 0;
#pragma unroll
            for (int k = 0; k < 8; ++k) {
                if (k < m) {
                    a0 = __hadd2(a0, u2h(va[k].x)); a1 = __hadd2(a1, u2h(va[k].y));
                    a2 = __hadd2(a2, u2h(va[k].z)); a3 = __hadd2(a3, u2h(va[k].w));
                }
            }
            b = bn; m = mn; bn = b3; mn = m3; idxN = idx3;
        }
        if (b >= end) break;
#pragma unroll
        for (int k = 0; k < 8; ++k) {
            int s0 = __shfl(idxN, k, 8);
            if (k < mn) va[k] = Hs4[(size_t)s0 * 8 + c];
        }
        {
            int b3 = bn + 8;
            int m3 = min(8, end - b3);
            int idx3 = (c < m3) ? (int)col[b3 + c] : 0;
#pragma unroll
            for (int k = 0; k < 8; ++k) {
                if (k < m) {
                    a0 = __hadd2(a0, u2h(vb[k].x)); a1 = __hadd2(a1, u2h(vb[k].y));
                    a2 = __hadd2(a2, u2h(vb[k].z)); a3 = __hadd2(a3, u2h(vb[k].w));
                }
            }
            b = bn; m = mn; bn = b3; mn = m3; idxN = idx3;
        }
    }
    float2 f0 = __half22float2(a0), f1 = __half22float2(a1);
    float2 f2 = __half22float2(a2), f3 = __half22float2(a3);
    float y0 = f0.x, y1 = f0.y, y2 = f1.x, y3 = f1.y;
    float y4 = f2.x, y5 = f2.y, y6 = f3.x, y7 = f3.y;
    if (valid) {
        float2 h0 = __half22float2(u2h(hv.x)), h1 = __half22float2(u2h(hv.y));
        float2 h2v = __half22float2(u2h(hv.z)), h3 = __half22float2(u2h(hv.w));
        float dv = dinv[dc];
        y0 = (y0 + h0.x) * dv; y1 = (y1 + h0.y) * dv;
        y2 = (y2 + h1.x) * dv; y3 = (y3 + h1.y) * dv;
        y4 = (y4 + h2v.x) * dv; y5 = (y5 + h2v.y) * dv;
        y6 = (y6 + h3.x) * dv; y7 = (y7 + h3.y) * dv;
    } else {
        y0 = y1 = y2 = y3 = y4 = y5 = y6 = y7 = 0.f;
    }
    *(float4*)&sS[slot][c * 8]     = make_float4(y0, y1, y2, y3);
    *(float4*)&sS[slot][c * 8 + 4] = make_float4(y4, y5, y6, y7);
    *(float4*)&sQ[slot][c * 8]     = make_float4(y0 * y0, y1 * y1, y2 * y2, y3 * y3);
    *(float4*)&sQ[slot][c * 8 + 4] = make_float4(y4 * y4, y5 * y5, y6 * y6, y7 * y7);
    if (c == 0) sG[slot] = valid ? batch[dc] : -1;
    __syncthreads();
    if (t < 64) {
        float s = 0.f, qq = 0.f;
#pragma unroll
        for (int i = 0; i < 32; ++i) { s += sS[i][t]; qq += sQ[i][t]; }
        float* dst = part + (size_t)(blockIdx.x & (NSLICE - 1)) * 128;
        atomicAdd(&dst[t], s);
        atomicAdd(&dst[64 + t], qq);
        int g0 = sG[0];
        bool same = (g0 >= 0);
#pragma unroll
        for (int i = 1; i < 32; ++i) same = same && (sG[i] == g0);
        if (same) {
            atomicAdd(&out[(size_t)g0 * 64 + t], s);
        } else {
#pragma unroll
            for (int i = 0; i < 32; ++i) {
                int gi = sG[i];
                if (gi >= 0) atomicAdd(&out[(size_t)gi * 64 + t], sS[i][t]);
            }
        }
    }
}

// ================= final: out = BN3-affine(graph mean), BN3 coeffs in-block =================

__global__ __launch_bounds__(256) void pool_div(float* __restrict__ out,
                                                const float* __restrict__ cnt,
                                                const float* __restrict__ part,
                                                const float* __restrict__ gamma,
                                                const float* __restrict__ beta,
                                                int G, float inv_n) {
    __shared__ float s_scsh[128];
    int t = threadIdx.x;
    if (t < 128) {
        float s = 0.f;
#pragma unroll
        for (int k = 0; k < NSLICE; ++k) s += part[k * 128 + t];
        s_scsh[t] = s;
    }
    __syncthreads();
    if (t < 64) {
        float mean = s_scsh[t] * inv_n;
        float var = s_scsh[64 + t] * inv_n - mean * mean;
        float sc = gamma[t] * rsqrtf(var + BN_EPS);
        s_scsh[t] = sc;
        s_scsh[64 + t] = beta[t] - mean * sc;
    }
    __syncthreads();
    int idx = blockIdx.x * 256 + t;
    if (idx >= G * 64) return;
    int j = idx & 63, g = idx >> 6;
    float c = cnt[g];
    out[idx] = (c > 0.5f) ? fmaf(s_scsh[j], out[idx] / c, s_scsh[64 + j]) : 0.f;
}

// ================= launch =================

extern "C" void kernel_launch(void* const* d_in, const int* in_sizes, int n_in,
                              void* d_out, int out_size, void* d_ws, size_t ws_size,
                              hipStream_t stream) {
    const float* x     = (const float*)d_in[0];
    const int*   ei    = (const int*)d_in[1];
    const int*   batch = (const int*)d_in[2];
    const float* Wl[3] = {(const float*)d_in[3], (const float*)d_in[7], (const float*)d_in[11]};
    const float* gl[3] = {(const float*)d_in[5], (const float*)d_in[9], (const float*)d_in[13]};
    const float* bl[3] = {(const float*)d_in[6], (const float*)d_in[10], (const float*)d_in[14]};
    float* out = (float*)d_out;

    int E = in_sizes[1] / 2;
    int n = in_sizes[0] / 64;
    int G = out_size / 64;
    const int* src = ei;
    const int* dst = ei + E;
    int NBC = (n + 255) / 256;  // coarse buckets (<=256 for n<=65536)
    float inv_n = 1.0f / (float)n;

    char* ws = (char*)d_ws;
    size_t off = 0;
    auto carve = [&](size_t bytes) {
        void* p = ws + off;
        off += (bytes + 255) & ~(size_t)255;
        return p;
    };
    // part + ccnt carved adjacently -> single memset covers both
    float*          part  = (float*)carve(3 * NSLICE * 128 * 4);  // 49152 B
    int*            ccnt  = (int*)carve(256 * 4);                  // 1024 B
    float*          dinv  = (float*)carve((size_t)n * 4);
    float*          cnt_g = (float*)carve((size_t)G * 4);
    unsigned*       Hs    = (unsigned*)carve((size_t)n * 32 * 4);  // n*64 fp16
    float*          Ybuf  = (float*)carve((size_t)n * 64 * 4);
    int*            rp    = (int*)carve(((size_t)n + 1) * 4);
    unsigned short* deg   = (unsigned short*)carve((size_t)n * 2);
    unsigned*       tmp   = (unsigned*)carve((size_t)NBC * CAP * 4);
    unsigned short* col   = (unsigned short*)carve((size_t)NBC * CAP * 2);

    int pgrid = (E + CCH - 1) / CCH;
    int gemm_grid = (n + 63) / 64;
    int agg_grid = (n + 31) / 32;

    // ---- setup: one small memset (part+ccnt), direct scatter, CSR build ----
    hipMemsetAsync(part, 0, 3 * NSLICE * 128 * 4 + 256 * 4, stream);
    scatter_direct<<<pgrid, 1024, 0, stream>>>(src, dst, ccnt, tmp, cnt_g, out, E, G);
    build_csr<<<NBC, 1024, 0, stream>>>(tmp, ccnt, rp, deg, col, dinv, batch, cnt_g, n, G);

    // ---- 3 GCN layers ----
    const float* cur = x;
    for (int l = 0; l < 3; ++l) {
        float* part_l = part + (size_t)l * NSLICE * 128;
        const float* part_prev = (l > 0) ? part + (size_t)(l - 1) * NSLICE * 128 : part;
        gemm64_v2<<<gemm_grid, 256, 0, stream>>>(cur, Wl[l], dinv, part_prev,
                                                 l > 0 ? gl[l - 1] : gl[0],
                                                 l > 0 ? bl[l - 1] : bl[0],
                                                 l > 0 ? 1 : 0, inv_n, Hs, n);
        if (l < 2) {
            agg<<<agg_grid, 256, 0, stream>>>((const uint4*)Hs, rp, deg, col, dinv,
                                              Ybuf, part_l, n);
        } else {
            agg_pool<<<agg_grid, 256, 0, stream>>>((const uint4*)Hs, rp, deg, col, dinv,
                                                   batch, out, part_l, n);
        }
        cur = Ybuf;
    }

    // ---- final BN3-affine on graph means (BN3 coeffs computed in-block) ----
    pool_div<<<(G * 64 + 255) / 256, 256, 0, stream>>>(out, cnt_g,
                                                       part + 2 * NSLICE * 128,
                                                       gl[2], bl[2], G, inv_n);
}

// Round 13
// 204.565 us; speedup vs baseline: 1.0356x; 1.0356x over previous
//
#include <hip/hip_runtime.h>
#include <hip/hip_fp16.h>

#define BN_EPS 1e-5f
#define CCH 2048   // edges per scatter block (391 blocks @ 1024 thr -> full CU coverage)
#define NSLICE 32  // stats partial slices (contention limiter)
#define OUT_CAP 8192
#define CAP 8192   // fixed bucket capacity (mean 4096, sd 64 -> >60 sigma margin)
#define SXS 68

// ---------------- fp16 helpers (union puns) ----------------

__device__ inline __half2 u2h(unsigned u) {
    union { unsigned u; __half2 h; } x; x.u = u; return x.h;
}
__device__ inline unsigned h2u(__half2 h) {
    union { unsigned u; __half2 h; } x; x.h = h; return x.u;
}
__device__ inline unsigned pack_f16x2(float a, float b) {
    return h2u(__floats2half2_rn(a, b));
}

// ================= Phase A: direct scatter into fixed-capacity buckets =================
// 1024 threads/block, 2048 edges/block: 2 edge iters; full CU coverage.

__global__ __launch_bounds__(1024) void scatter_direct(const int* __restrict__ src,
                                                       const int* __restrict__ dst,
                                                       int* __restrict__ ccnt,
                                                       unsigned* __restrict__ tmp,
                                                       float* __restrict__ cnt_g,
                                                       float* __restrict__ out,
                                                       int E, int G) {
    __shared__ int lcnt[256];
    int t = threadIdx.x;
    int tid = blockIdx.x * 1024 + t;
    int stride = gridDim.x * 1024;
    for (int i = tid; i < G * 64; i += stride) out[i] = 0.f;
    for (int i = tid; i < G; i += stride) cnt_g[i] = 0.f;

    int e0 = blockIdx.x * CCH;
    if (t < 256) lcnt[t] = 0;
    __syncthreads();
#pragma unroll
    for (int k = 0; k < CCH / 1024; ++k) {
        int e = e0 + k * 1024 + t;
        if (e < E) atomicAdd(&lcnt[dst[e] >> 8], 1);
    }
    __syncthreads();
    int c = (t < 256) ? lcnt[t] : 0;
    __syncthreads();
    if (t < 256 && c > 0) lcnt[t] = t * CAP + atomicAdd(&ccnt[t], c);  // absolute run start
    __syncthreads();
#pragma unroll
    for (int k = 0; k < CCH / 1024; ++k) {
        int e = e0 + k * 1024 + t;
        if (e < E) {
            int d = dst[e];
            int pos = atomicAdd(&lcnt[d >> 8], 1);
            tmp[pos] = ((unsigned)src[e] << 8) | (unsigned)(d & 255);
        }
    }
}

// ================= Phase B: per-bucket counting sort -> CSR (rp, deg, u16 col) + dinv
//            1024 threads; barrier-free wave-scan (shfl_up) + 1-barrier combine =========

__global__ __launch_bounds__(1024) void build_csr(const unsigned* __restrict__ tmp,
                                                  const int* __restrict__ ccnt,
                                                  int* __restrict__ rp,
                                                  unsigned short* __restrict__ deg,
                                                  unsigned short* __restrict__ col,
                                                  float* __restrict__ dinv,
                                                  const int* __restrict__ batch,
                                                  float* __restrict__ cnt_g,
                                                  int n, int G) {
    __shared__ int hist[256];
    __shared__ unsigned short outw[OUT_CAP];
    __shared__ int h[512];
    __shared__ int wsum[4];
    int b = blockIdx.x;
    int t = threadIdx.x;
    int beg = b * CAP;
    int m = ccnt[b];
    int end = beg + m;
    if (t < 256) hist[t] = 0;
    __syncthreads();
    for (int e = beg + t; e < end; e += 1024) atomicAdd(&hist[tmp[e] & 255u], 1);
    __syncthreads();
    // exclusive scan over 256 bins: 4 waves scan via shfl_up, then combine
    int v = 0, x = 0;
    if (t < 256) {
        v = hist[t];
        x = v;
#pragma unroll
        for (int off = 1; off < 64; off <<= 1) {
            int y = __shfl_up(x, off, 64);
            if ((t & 63) >= off) x += y;
        }
        if ((t & 63) == 63) wsum[t >> 6] = x;   // wave inclusive total
    }
    __syncthreads();
    if (t < 256) {
        int w = t >> 6;
        int pre = 0;
        if (w > 0) pre += wsum[0];
        if (w > 1) pre += wsum[1];
        if (w > 2) pre += wsum[2];
        int excl = (x + pre) - v;
        int node = b * 256 + t;
        if (node < n) {
            dinv[node] = rsqrtf(1.0f + (float)v);
            rp[node] = beg + excl;
            deg[node] = (unsigned short)v;
        }
        hist[t] = excl;  // becomes cursor
    }
    __syncthreads();
    if (m <= OUT_CAP) {
        for (int e = beg + t; e < end; e += 1024) {
            unsigned p = tmp[e];
            int pos = atomicAdd(&hist[p & 255u], 1);
            outw[pos] = (unsigned short)(p >> 8);
        }
        __syncthreads();
        for (int i = t; i < m; i += 1024) col[beg + i] = outw[i];
    } else {  // overflow fallback (dead for CAP==OUT_CAP, kept for safety)
        for (int e = beg + t; e < end; e += 1024) {
            unsigned p = tmp[e];
            int pos = atomicAdd(&hist[p & 255u], 1);
            col[beg + pos] = (unsigned short)(p >> 8);
        }
    }
    // ---- fused graph-size histogram ----
    if (G <= 512) {
        __syncthreads();
        for (int i = t; i < 512; i += 1024) h[i] = 0;
        __syncthreads();
        for (int i = b * 1024 + t; i < n; i += gridDim.x * 1024)
            atomicAdd(&h[batch[i]], 1);
        __syncthreads();
        for (int i = t; i < G; i += 1024)
            if (h[i]) atomicAdd(&cnt_g[i], (float)h[i]);
    } else {
        for (int i = b * 1024 + t; i < n; i += gridDim.x * 1024)
            atomicAdd(&cnt_g[batch[i]], 1.0f);
    }
}

// ================= GEMM: Hs(fp16) = BNReLU(X) @ W * dinv[row] =================

__global__ __launch_bounds__(256) void gemm64_v2(const float* __restrict__ X,
                                                 const float* __restrict__ W,
                                                 const float* __restrict__ dinv,
                                                 const float* __restrict__ part,
                                                 const float* __restrict__ gamma,
                                                 const float* __restrict__ beta,
                                                 int has_bn, float inv_n,
                                                 unsigned* __restrict__ Hs, int n) {
    __shared__ float sX[64 * SXS];
    __shared__ float sW[64 * SXS];
    __shared__ float s_scsh[128];
    int t = threadIdx.x;
    int c4 = t & 15;
    int base = blockIdx.x * 64;

    if (has_bn) {
        if (t < 128) {
            float s = 0.f;
#pragma unroll
            for (int k = 0; k < NSLICE; ++k) s += part[k * 128 + t];
            s_scsh[t] = s;
        }
        __syncthreads();
        if (t < 64) {
            float mean = s_scsh[t] * inv_n;
            float var = s_scsh[64 + t] * inv_n - mean * mean;
            float sc = gamma[t] * rsqrtf(var + BN_EPS);
            s_scsh[t] = sc;
            s_scsh[64 + t] = beta[t] - mean * sc;
        }
        __syncthreads();
    }

    {
        const float4* W4 = (const float4*)W;
#pragma unroll
        for (int it = 0; it < 4; ++it) {
            int idx = it * 256 + t;
            int r = idx >> 4;
            float4 v = W4[r * 16 + c4];
            *(float4*)&sW[r * SXS + c4 * 4] = v;
        }
    }
    {
        const float4* X4 = (const float4*)X;
        float4 sc4, sh4;
        if (has_bn) {
            sc4 = *(const float4*)&s_scsh[c4 * 4];
            sh4 = *(const float4*)&s_scsh[64 + c4 * 4];
        }
#pragma unroll
        for (int it = 0; it < 4; ++it) {
            int idx = it * 256 + t;
            int r = idx >> 4;
            int grow = base + r;
            float4 v = make_float4(0.f, 0.f, 0.f, 0.f);
            if (grow < n) v = X4[(size_t)grow * 16 + c4];
            if (has_bn) {
                v.x = fmaxf(fmaf(v.x, sc4.x, sh4.x), 0.f);
                v.y = fmaxf(fmaf(v.y, sc4.y, sh4.y), 0.f);
                v.z = fmaxf(fmaf(v.z, sc4.z, sh4.z), 0.f);
                v.w = fmaxf(fmaf(v.w, sc4.w, sh4.w), 0.f);
            }
            *(float4*)&sX[r * SXS + c4 * 4] = v;
        }
    }
    __syncthreads();

    int rgrp = t >> 4;
    float4 acc[4];
#pragma unroll
    for (int ri = 0; ri < 4; ++ri) acc[ri] = make_float4(0.f, 0.f, 0.f, 0.f);

#pragma unroll 4
    for (int k4 = 0; k4 < 16; ++k4) {
        float4 xv[4], wv[4];
#pragma unroll
        for (int ri = 0; ri < 4; ++ri)
            xv[ri] = *(const float4*)&sX[(rgrp + 16 * ri) * SXS + k4 * 4];
#pragma unroll
        for (int kk = 0; kk < 4; ++kk)
            wv[kk] = *(const float4*)&sW[(k4 * 4 + kk) * SXS + c4 * 4];
#pragma unroll
        for (int ri = 0; ri < 4; ++ri) {
            acc[ri].x = fmaf(xv[ri].x, wv[0].x, acc[ri].x);
            acc[ri].y = fmaf(xv[ri].x, wv[0].y, acc[ri].y);
            acc[ri].z = fmaf(xv[ri].x, wv[0].z, acc[ri].z);
            acc[ri].w = fmaf(xv[ri].x, wv[0].w, acc[ri].w);
            acc[ri].x = fmaf(xv[ri].y, wv[1].x, acc[ri].x);
            acc[ri].y = fmaf(xv[ri].y, wv[1].y, acc[ri].y);
            acc[ri].z = fmaf(xv[ri].y, wv[1].z, acc[ri].z);
            acc[ri].w = fmaf(xv[ri].y, wv[1].w, acc[ri].w);
            acc[ri].x = fmaf(xv[ri].z, wv[2].x, acc[ri].x);
            acc[ri].y = fmaf(xv[ri].z, wv[2].y, acc[ri].y);
            acc[ri].z = fmaf(xv[ri].z, wv[2].z, acc[ri].z);
            acc[ri].w = fmaf(xv[ri].z, wv[2].w, acc[ri].w);
            acc[ri].x = fmaf(xv[ri].w, wv[3].x, acc[ri].x);
            acc[ri].y = fmaf(xv[ri].w, wv[3].y, acc[ri].y);
            acc[ri].z = fmaf(xv[ri].w, wv[3].z, acc[ri].z);
            acc[ri].w = fmaf(xv[ri].w, wv[3].w, acc[ri].w);
        }
    }

#pragma unroll
    for (int ri = 0; ri < 4; ++ri) {
        int row = base + rgrp + 16 * ri;
        if (row < n) {
            float dv = dinv[row];
            uint2 o2;
            o2.x = pack_f16x2(acc[ri].x * dv, acc[ri].y * dv);
            o2.y = pack_f16x2(acc[ri].z * dv, acc[ri].w * dv);
            ((uint2*)Hs)[(size_t)row * 16 + c4] = o2;
        }
    }
}

// ================= CSR gather-aggregate: 8 dsts per wave, 8-lane clusters ============
// Self-row load hoisted above the loop; next chunk's col indices prefetched before
// consuming the current chunk's row loads (hides index latency under packed adds).

__global__ __launch_bounds__(256) void agg(const uint4* __restrict__ Hs4,
                                           const int* __restrict__ rp,
                                           const unsigned short* __restrict__ deg,
                                           const unsigned short* __restrict__ col,
                                           const float* __restrict__ dinv,
                                           float* __restrict__ Y,
                                           float* __restrict__ part, int n) {
    __shared__ float sS[32][64];
    __shared__ float sQ[32][64];
    int t = threadIdx.x;
    int w = t >> 6;
    int lane = t & 63;
    int dslot = lane >> 3;   // dst within wave (0..7)
    int c = lane & 7;        // column chunk (16B of the 128B row) AND index lane
    int slot = w * 8 + dslot;
    int d = blockIdx.x * 32 + slot;
    bool valid = d < n;
    int dc = valid ? d : 0;
    // hoisted self-row load: in flight during the whole gather loop
    uint4 hv = make_uint4(0u, 0u, 0u, 0u);
    if (valid) hv = Hs4[(size_t)dc * 8 + c];
    __half2 a0 = u2h(0u), a1 = u2h(0u), a2 = u2h(0u), a3 = u2h(0u);
    int beg = 0, end = 0;
    if (valid) { beg = rp[dc]; end = beg + (int)deg[dc]; }
    int b = beg;
    int m = min(8, end - b);
    int myidx = (c < m) ? (int)col[b + c] : 0;
    while (b < end) {
        int bn = b + 8;
        int mn = min(8, end - bn);                    // may be <= 0 on last chunk
        int nidx = (c < mn) ? (int)col[bn + c] : 0;   // prefetch next chunk's indices
        uint4 v[8];
#pragma unroll
        for (int k = 0; k < 8; ++k) {
            int s0 = __shfl(myidx, k, 8);    // broadcast neighbor k's row index
            if (k < m) v[k] = Hs4[(size_t)s0 * 8 + c];
        }
#pragma unroll
        for (int k = 0; k < 8; ++k) {
            if (k < m) {
                a0 = __hadd2(a0, u2h(v[k].x)); a1 = __hadd2(a1, u2h(v[k].y));
                a2 = __hadd2(a2, u2h(v[k].z)); a3 = __hadd2(a3, u2h(v[k].w));
            }
        }
        b = bn; m = mn; myidx = nidx;
    }
    // every lane holds the complete sums for its 8 columns -- no reduction needed
    float2 f0 = __half22float2(a0), f1 = __half22float2(a1);
    float2 f2 = __half22float2(a2), f3 = __half22float2(a3);
    float y0 = f0.x, y1 = f0.y, y2 = f1.x, y3 = f1.y;
    float y4 = f2.x, y5 = f2.y, y6 = f3.x, y7 = f3.y;
    if (valid) {
        float2 h0 = __half22float2(u2h(hv.x)), h1 = __half22float2(u2h(hv.y));
        float2 h2v = __half22float2(u2h(hv.z)), h3 = __half22float2(u2h(hv.w));
        float dv = dinv[dc];
        y0 = (y0 + h0.x) * dv; y1 = (y1 + h0.y) * dv;
        y2 = (y2 + h1.x) * dv; y3 = (y3 + h1.y) * dv;
        y4 = (y4 + h2v.x) * dv; y5 = (y5 + h2v.y) * dv;
        y6 = (y6 + h3.x) * dv; y7 = (y7 + h3.y) * dv;
        *(float4*)&Y[(size_t)dc * 64 + c * 8]     = make_float4(y0, y1, y2, y3);
        *(float4*)&Y[(size_t)dc * 64 + c * 8 + 4] = make_float4(y4, y5, y6, y7);
    } else {
        y0 = y1 = y2 = y3 = y4 = y5 = y6 = y7 = 0.f;
    }
    *(float4*)&sS[slot][c * 8]     = make_float4(y0, y1, y2, y3);
    *(float4*)&sS[slot][c * 8 + 4] = make_float4(y4, y5, y6, y7);
    *(float4*)&sQ[slot][c * 8]     = make_float4(y0 * y0, y1 * y1, y2 * y2, y3 * y3);
    *(float4*)&sQ[slot][c * 8 + 4] = make_float4(y4 * y4, y5 * y5, y6 * y6, y7 * y7);
    __syncthreads();
    if (t < 64) {
        float s = 0.f, qq = 0.f;
#pragma unroll
        for (int i = 0; i < 32; ++i) { s += sS[i][t]; qq += sQ[i][t]; }
        float* dst = part + (size_t)(blockIdx.x & (NSLICE - 1)) * 128;
        atomicAdd(&dst[t], s);
        atomicAdd(&dst[64 + t], qq);
    }
}

// layer-3 variant: no Y materialization; per-graph raw-y sums via atomics.
__global__ __launch_bounds__(256) void agg_pool(const uint4* __restrict__ Hs4,
                                                const int* __restrict__ rp,
                                                const unsigned short* __restrict__ deg,
                                                const unsigned short* __restrict__ col,
                                                const float* __restrict__ dinv,
                                                const int* __restrict__ batch,
                                                float* __restrict__ out,
                                                float* __restrict__ part, int n) {
    __shared__ float sS[32][64];
    __shared__ float sQ[32][64];
    __shared__ int sG[32];
    int t = threadIdx.x;
    int w = t >> 6;
    int lane = t & 63;
    int dslot = lane >> 3;
    int c = lane & 7;
    int slot = w * 8 + dslot;
    int d = blockIdx.x * 32 + slot;
    bool valid = d < n;
    int dc = valid ? d : 0;
    uint4 hv = make_uint4(0u, 0u, 0u, 0u);
    if (valid) hv = Hs4[(size_t)dc * 8 + c];
    __half2 a0 = u2h(0u), a1 = u2h(0u), a2 = u2h(0u), a3 = u2h(0u);
    int beg = 0, end = 0;
    if (valid) { beg = rp[dc]; end = beg + (int)deg[dc]; }
    int b = beg;
    int m = min(8, end - b);
    int myidx = (c < m) ? (int)col[b + c] : 0;
    while (b < end) {
        int bn = b + 8;
        int mn = min(8, end - bn);
        int nidx = (c < mn) ? (int)col[bn + c] : 0;
        uint4 v[8];
#pragma unroll
        for (int k = 0; k < 8; ++k) {
            int s0 = __shfl(myidx, k, 8);
            if (k < m) v[k] = Hs4[(size_t)s0 * 8 + c];
        }
#pragma unroll
        for (int k = 0; k < 8; ++k) {
            if (k < m) {
                a0 = __hadd2(a0, u2h(v[k].x)); a1 = __hadd2(a1, u2h(v[k].y));
                a2 = __hadd2(a2, u2h(v[k].z)); a3 = __hadd2(a3, u2h(v[k].w));
            }
        }
        b = bn; m = mn; myidx = nidx;
    }
    float2 f0 = __half22float2(a0), f1 = __half22float2(a1);
    float2 f2 = __half22float2(a2), f3 = __half22float2(a3);
    float y0 = f0.x, y1 = f0.y, y2 = f1.x, y3 = f1.y;
    float y4 = f2.x, y5 = f2.y, y6 = f3.x, y7 = f3.y;
    if (valid) {
        float2 h0 = __half22float2(u2h(hv.x)), h1 = __half22float2(u2h(hv.y));
        float2 h2v = __half22float2(u2h(hv.z)), h3 = __half22float2(u2h(hv.w));
        float dv = dinv[dc];
        y0 = (y0 + h0.x) * dv; y1 = (y1 + h0.y) * dv;
        y2 = (y2 + h1.x) * dv; y3 = (y3 + h1.y) * dv;
        y4 = (y4 + h2v.x) * dv; y5 = (y5 + h2v.y) * dv;
        y6 = (y6 + h3.x) * dv; y7 = (y7 + h3.y) * dv;
    } else {
        y0 = y1 = y2 = y3 = y4 = y5 = y6 = y7 = 0.f;
    }
    *(float4*)&sS[slot][c * 8]     = make_float4(y0, y1, y2, y3);
    *(float4*)&sS[slot][c * 8 + 4] = make_float4(y4, y5, y6, y7);
    *(float4*)&sQ[slot][c * 8]     = make_float4(y0 * y0, y1 * y1, y2 * y2, y3 * y3);
    *(float4*)&sQ[slot][c * 8 + 4] = make_float4(y4 * y4, y5 * y5, y6 * y6, y7 * y7);
    if (c == 0) sG[slot] = valid ? batch[dc] : -1;
    __syncthreads();
    if (t < 64) {
        float s = 0.f, qq = 0.f;
#pragma unroll
        for (int i = 0; i < 32; ++i) { s += sS[i][t]; qq += sQ[i][t]; }
        float* dst = part + (size_t)(blockIdx.x & (NSLICE - 1)) * 128;
        atomicAdd(&dst[t], s);
        atomicAdd(&dst[64 + t], qq);
        int g0 = sG[0];
        bool same = (g0 >= 0);
#pragma unroll
        for (int i = 1; i < 32; ++i) same = same && (sG[i] == g0);
        if (same) {
            atomicAdd(&out[(size_t)g0 * 64 + t], s);
        } else {
#pragma unroll
            for (int i = 0; i < 32; ++i) {
                int gi = sG[i];
                if (gi >= 0) atomicAdd(&out[(size_t)gi * 64 + t], sS[i][t]);
            }
        }
    }
}

// ================= final: out = BN3-affine(graph mean), BN3 coeffs in-block =================

__global__ __launch_bounds__(256) void pool_div(float* __restrict__ out,
                                                const float* __restrict__ cnt,
                                                const float* __restrict__ part,
                                                const float* __restrict__ gamma,
                                                const float* __restrict__ beta,
                                                int G, float inv_n) {
    __shared__ float s_scsh[128];
    int t = threadIdx.x;
    if (t < 128) {
        float s = 0.f;
#pragma unroll
        for (int k = 0; k < NSLICE; ++k) s += part[k * 128 + t];
        s_scsh[t] = s;
    }
    __syncthreads();
    if (t < 64) {
        float mean = s_scsh[t] * inv_n;
        float var = s_scsh[64 + t] * inv_n - mean * mean;
        float sc = gamma[t] * rsqrtf(var + BN_EPS);
        s_scsh[t] = sc;
        s_scsh[64 + t] = beta[t] - mean * sc;
    }
    __syncthreads();
    int idx = blockIdx.x * 256 + t;
    if (idx >= G * 64) return;
    int j = idx & 63, g = idx >> 6;
    float c = cnt[g];
    out[idx] = (c > 0.5f) ? fmaf(s_scsh[j], out[idx] / c, s_scsh[64 + j]) : 0.f;
}

// ================= launch =================

extern "C" void kernel_launch(void* const* d_in, const int* in_sizes, int n_in,
                              void* d_out, int out_size, void* d_ws, size_t ws_size,
                              hipStream_t stream) {
    const float* x     = (const float*)d_in[0];
    const int*   ei    = (const int*)d_in[1];
    const int*   batch = (const int*)d_in[2];
    const float* Wl[3] = {(const float*)d_in[3], (const float*)d_in[7], (const float*)d_in[11]};
    const float* gl[3] = {(const float*)d_in[5], (const float*)d_in[9], (const float*)d_in[13]};
    const float* bl[3] = {(const float*)d_in[6], (const float*)d_in[10], (const float*)d_in[14]};
    float* out = (float*)d_out;

    int E = in_sizes[1] / 2;
    int n = in_sizes[0] / 64;
    int G = out_size / 64;
    const int* src = ei;
    const int* dst = ei + E;
    int NBC = (n + 255) / 256;  // coarse buckets (<=256 for n<=65536)
    float inv_n = 1.0f / (float)n;

    char* ws = (char*)d_ws;
    size_t off = 0;
    auto carve = [&](size_t bytes) {
        void* p = ws + off;
        off += (bytes + 255) & ~(size_t)255;
        return p;
    };
    // part + ccnt carved adjacently -> single memset covers both
    float*          part  = (float*)carve(3 * NSLICE * 128 * 4);  // 49152 B
    int*            ccnt  = (int*)carve(256 * 4);                  // 1024 B
    float*          dinv  = (float*)carve((size_t)n * 4);
    float*          cnt_g = (float*)carve((size_t)G * 4);
    unsigned*       Hs    = (unsigned*)carve((size_t)n * 32 * 4);  // n*64 fp16
    float*          Ybuf  = (float*)carve((size_t)n * 64 * 4);
    int*            rp    = (int*)carve(((size_t)n + 1) * 4);
    unsigned short* deg   = (unsigned short*)carve((size_t)n * 2);
    unsigned*       tmp   = (unsigned*)carve((size_t)NBC * CAP * 4);
    unsigned short* col   = (unsigned short*)carve((size_t)NBC * CAP * 2);

    int pgrid = (E + CCH - 1) / CCH;
    int gemm_grid = (n + 63) / 64;
    int agg_grid = (n + 31) / 32;

    // ---- setup: one small memset (part+ccnt), direct scatter, CSR build ----
    hipMemsetAsync(part, 0, 3 * NSLICE * 128 * 4 + 256 * 4, stream);
    scatter_direct<<<pgrid, 1024, 0, stream>>>(src, dst, ccnt, tmp, cnt_g, out, E, G);
    build_csr<<<NBC, 1024, 0, stream>>>(tmp, ccnt, rp, deg, col, dinv, batch, cnt_g, n, G);

    // ---- 3 GCN layers ----
    const float* cur = x;
    for (int l = 0; l < 3; ++l) {
        float* part_l = part + (size_t)l * NSLICE * 128;
        const float* part_prev = (l > 0) ? part + (size_t)(l - 1) * NSLICE * 128 : part;
        gemm64_v2<<<gemm_grid, 256, 0, stream>>>(cur, Wl[l], dinv, part_prev,
                                                 l > 0 ? gl[l - 1] : gl[0],
                                                 l > 0 ? bl[l - 1] : bl[0],
                                                 l > 0 ? 1 : 0, inv_n, Hs, n);
        if (l < 2) {
            agg<<<agg_grid, 256, 0, stream>>>((const uint4*)Hs, rp, deg, col, dinv,
                                              Ybuf, part_l, n);
        } else {
            agg_pool<<<agg_grid, 256, 0, stream>>>((const uint4*)Hs, rp, deg, col, dinv,
                                                   batch, out, part_l, n);
        }
        cur = Ybuf;
    }

    // ---- final BN3-affine on graph means (BN3 coeffs computed in-block) ----
    pool_div<<<(G * 64 + 255) / 256, 256, 0, stream>>>(out, cnt_g,
                                                       part + 2 * NSLICE * 128,
                                                       gl[2], bl[2], G, inv_n);
}